// Round 1
// baseline (2638.709 us; speedup 1.0000x reference)
//
#include <hip/hip_runtime.h>
#include <stdint.h>
#include <math.h>

#define B_    2048
#define DIN_  512
#define H_    768
#define A_    5001
#define RL_   4
#define NDATA_ 56000.0f

// ---------------- threefry2x32 (exact JAX semantics) ----------------
__host__ __device__ __forceinline__ void threefry2x32(
    uint32_t k0, uint32_t k1, uint32_t x0, uint32_t x1,
    uint32_t* o0, uint32_t* o1)
{
  const uint32_t ks2 = k0 ^ k1 ^ 0x1BD11BDAu;
#define TF_R(r) { x0 += x1; x1 = (x1 << (r)) | (x1 >> (32 - (r))); x1 ^= x0; }
  x0 += k0; x1 += k1;
  TF_R(13) TF_R(15) TF_R(26) TF_R(6)
  x0 += k1;  x1 += ks2 + 1u;
  TF_R(17) TF_R(29) TF_R(16) TF_R(24)
  x0 += ks2; x1 += k0 + 2u;
  TF_R(13) TF_R(15) TF_R(26) TF_R(6)
  x0 += k0;  x1 += k1 + 3u;
  TF_R(17) TF_R(29) TF_R(16) TF_R(24)
  x0 += k1;  x1 += ks2 + 4u;
  TF_R(13) TF_R(15) TF_R(26) TF_R(6)
  x0 += ks2; x1 += k0 + 5u;
#undef TF_R
  *o0 = x0; *o1 = x1;
}

// gumbel for flat element n of the (B,A) uniform draw, partitionable scheme:
// counter = (hi=0, lo=n), bits = o0 ^ o1; uniform in [1e-6, 1-1e-6); g=-log(-log(u))
__device__ __forceinline__ float gumbel_for(uint32_t k0, uint32_t k1, uint32_t n)
{
  uint32_t o0, o1;
  threefry2x32(k0, k1, 0u, n, &o0, &o1);
  const uint32_t bits = o0 ^ o1;
  const float f = __uint_as_float((bits >> 9) | 0x3f800000u);  // [1,2)
  const float minv = 1e-6f;
  const float maxv = 1.0f - 1e-6f;
  const float span = maxv - minv;
  // match XLA elementwise order: f*span + minv - span, no FMA contraction
  float u = __fmul_rn(f, span);
  u = __fadd_rn(u, minv);
  u = __fsub_rn(u, span);
  u = fmaxf(minv, u);
  return -logf(-logf(u));
}

// ---------------- fp32 GEMM: C[M,N] = A[M,K] @ W[N,K]^T + bias, opt ReLU ----
template<int BM, int BN, int BK, int TM, int TN, int ACT>
__global__ __launch_bounds__((BM / TM) * (BN / TN))
void gemm_nt(const float* __restrict__ A, const float* __restrict__ W,
             const float* __restrict__ bias, float* __restrict__ C,
             int M, int N, int K)
{
  constexpr int TX = BN / TN;
  constexpr int TY = BM / TM;
  constexpr int NT = TX * TY;
  constexpr int PAD = 4;              // keeps 16B row alignment, breaks pow2 stride
  constexpr int KF4 = BK / 4;
  constexpr int AF4 = BM * KF4;
  constexpr int BF4 = BN * KF4;
  static_assert(AF4 % NT == 0 && BF4 % NT == 0, "staging divisibility");

  __shared__ float As[BK][BM + PAD];
  __shared__ float Bs[BK][BN + PAD];

  const int tid = threadIdx.x;
  const int tx = tid % TX;
  const int ty = tid / TX;
  const int bm = blockIdx.y * BM;
  const int bn = blockIdx.x * BN;

  float acc[TM][TN];
#pragma unroll
  for (int i = 0; i < TM; ++i)
#pragma unroll
    for (int j = 0; j < TN; ++j) acc[i][j] = 0.f;

  for (int k0 = 0; k0 < K; k0 += BK) {
#pragma unroll
    for (int it = 0; it < AF4 / NT; ++it) {
      const int f = tid + it * NT;
      const int row = f / KF4, c4 = f % KF4;
      const float4 v = *(const float4*)(A + (size_t)(bm + row) * K + k0 + 4 * c4);
      As[4 * c4 + 0][row] = v.x; As[4 * c4 + 1][row] = v.y;
      As[4 * c4 + 2][row] = v.z; As[4 * c4 + 3][row] = v.w;
    }
#pragma unroll
    for (int it = 0; it < BF4 / NT; ++it) {
      const int f = tid + it * NT;
      const int row = f / KF4, c4 = f % KF4;
      float4 v = make_float4(0.f, 0.f, 0.f, 0.f);
      if (bn + row < N)
        v = *(const float4*)(W + (size_t)(bn + row) * K + k0 + 4 * c4);
      Bs[4 * c4 + 0][row] = v.x; Bs[4 * c4 + 1][row] = v.y;
      Bs[4 * c4 + 2][row] = v.z; Bs[4 * c4 + 3][row] = v.w;
    }
    __syncthreads();
#pragma unroll
    for (int k = 0; k < BK; ++k) {
      float av[TM], bv[TN];
#pragma unroll
      for (int i = 0; i < TM; i += 4)
        *(float4*)&av[i] = *(const float4*)&As[k][ty * TM + i];
#pragma unroll
      for (int j = 0; j < TN; j += 4)
        *(float4*)&bv[j] = *(const float4*)&Bs[k][tx * TN + j];
#pragma unroll
      for (int i = 0; i < TM; ++i)
#pragma unroll
        for (int j = 0; j < TN; ++j)
          acc[i][j] = fmaf(av[i], bv[j], acc[i][j]);
    }
    __syncthreads();
  }

#pragma unroll
  for (int i = 0; i < TM; ++i) {
    const int m = bm + ty * TM + i;
#pragma unroll
    for (int j = 0; j < TN; ++j) {
      const int n = bn + tx * TN + j;
      if (n < N) {
        float v = acc[i][j] + bias[n];
        if (ACT) v = fmaxf(v, 0.f);
        C[(size_t)m * N + n] = v;
      }
    }
  }
}

// ---------------- mask init (+ step-0 row_zero fix) ----------------
__global__ __launch_bounds__(256)
void mask_init(const int* __restrict__ xmask, uint8_t* __restrict__ mask)
{
  const int b = blockIdx.x, tid = threadIdx.x;
  int s = 0;
  for (int a = tid; a < A_; a += 256) {
    const int m = (xmask[(size_t)b * A_ + a] != 0) ? 1 : 0;
    mask[(size_t)b * A_ + a] = (uint8_t)m;
    s += m;
  }
  __shared__ int red[256];
  red[tid] = s; __syncthreads();
  for (int t = 128; t > 0; t >>= 1) {
    if (tid < t) red[tid] += red[tid + t];
    __syncthreads();
  }
  if (tid == 0 && red[0] == 0) mask[(size_t)b * A_] = 1;
}

// ---------------- GRU elementwise (r,z,n gate order, torch layout) ----------
__global__ __launch_bounds__(256)
void gru_elem(const float* __restrict__ gi, const float* __restrict__ gh,
              const float* __restrict__ bhh, float* __restrict__ h, int first)
{
  const int i = blockIdx.x * 256 + threadIdx.x;
  if (i >= B_ * H_) return;
  const int b = i / H_;
  const int d = i - b * H_;
  const float* gib = gi + (size_t)b * 3 * H_;
  const float ir = gib[d], iz = gib[H_ + d], in_ = gib[2 * H_ + d];
  float hr, hz, hn, hp;
  if (first) {            // h == 0 -> gh = b_hh exactly (saves a full GEMM)
    hr = bhh[d]; hz = bhh[H_ + d]; hn = bhh[2 * H_ + d]; hp = 0.f;
  } else {
    const float* ghb = gh + (size_t)b * 3 * H_;
    hr = ghb[d]; hz = ghb[H_ + d]; hn = ghb[2 * H_ + d]; hp = h[i];
  }
  const float r = 1.f / (1.f + expf(-(ir + hr)));
  const float z = 1.f / (1.f + expf(-(iz + hz)));
  const float n = tanhf(in_ + r * hn);
  h[i] = (1.f - z) * n + z * hp;
}

// ---------------- per-step masked gumbel argmax + mask/cur update ----------
__global__ __launch_bounds__(256)
void select_step(const float* __restrict__ logits, uint8_t* __restrict__ mask,
                 int* __restrict__ idxs, const float* __restrict__ cls,
                 const float* __restrict__ ae, float* __restrict__ cur,
                 float* __restrict__ atomp, uint32_t k0, uint32_t k1, int step)
{
  const int b = blockIdx.x, tid = threadIdx.x;
  uint8_t* mrow = mask + (size_t)b * A_;

  if (step > 0) {
    const int prev = idxs[(step - 1) * B_ + b];
    if (prev == 0) {
      for (int a = tid; a < A_; a += 256) mrow[a] = 0;
    }
    __syncthreads();
    if (tid == 0) mrow[0] = 1;
    __syncthreads();
  }

  const float* lrow = logits + (size_t)b * A_;
  const uint32_t nbase = (uint32_t)b * (uint32_t)A_;
  float bv = -INFINITY;
  int bi = A_;
  for (int a = tid; a < A_; a += 256) {
    if (mrow[a]) {
      const float v = lrow[a] + gumbel_for(k0, k1, nbase + (uint32_t)a);
      if (v > bv) { bv = v; bi = a; }   // strictly >, a increasing -> first-max kept
    }
  }
  __shared__ float sv[256];
  __shared__ int   si[256];
  sv[tid] = bv; si[tid] = bi;
  __syncthreads();
  for (int s = 128; s > 0; s >>= 1) {
    if (tid < s) {
      const float v2 = sv[tid + s]; const int i2 = si[tid + s];
      if (v2 > sv[tid] || (v2 == sv[tid] && i2 < si[tid])) { sv[tid] = v2; si[tid] = i2; }
    }
    __syncthreads();
  }
  const int sel = si[0];
  if (tid == 0) {
    mrow[sel] = 0;
    idxs[step * B_ + b] = sel;
    atomp[(size_t)b * (RL_ * A_) + (size_t)step * A_ + sel] = 1.0f;
  }
  const float* aerow = ae + (size_t)sel * H_;
  const float* clsr  = cls + (size_t)b * H_;
  float* curr = cur + (size_t)b * H_;
  for (int d = tid; d < H_; d += 256) curr[d] = clsr[d] + aerow[d];
}

// ---------------- final heads: mu/coverage -> cp, out=log(cp) --------------
__global__ __launch_bounds__(256)
void head_k(const int* __restrict__ idxs, const float* __restrict__ ae,
            const float* __restrict__ w_mu, const float* __restrict__ b_mu,
            const float* __restrict__ w_cov, const float* __restrict__ b_cov,
            const float* __restrict__ alpha, float* __restrict__ outf)
{
  const int b = blockIdx.x, tid = threadIdx.x;
  const int i0 = idxs[0 * B_ + b], i1 = idxs[1 * B_ + b];
  const int i2 = idxs[2 * B_ + b], i3 = idxs[3 * B_ + b];
  const float* r0 = ae + (size_t)i0 * H_;
  const float* r1 = ae + (size_t)i1 * H_;
  const float* r2 = ae + (size_t)i2 * H_;
  const float* r3 = ae + (size_t)i3 * H_;
  float pmu = 0.f, pcv = 0.f;
  for (int d = tid; d < H_; d += 256) {
    const float a = r0[d] + r1[d] + r2[d] + r3[d];
    pmu += a * w_mu[d];
    pcv += a * w_cov[d];
  }
  __shared__ float smu[256], scv[256];
  smu[tid] = pmu; scv[tid] = pcv;
  __syncthreads();
  for (int s = 128; s > 0; s >>= 1) {
    if (tid < s) { smu[tid] += smu[tid + s]; scv[tid] += scv[tid + s]; }
    __syncthreads();
  }
  if (tid == 0) {
    const float mu = 1.f / (1.f + expf(-(smu[0] + b_mu[0])));
    const float cv = 1.f / (1.f + expf(-(scv[0] + b_cov[0])));
    const float n = cv * NDATA_;
    const float inv = alpha[0] / n;
    const float pp = (mu + inv) / (1.f + 2.f * inv);
    outf[2 * b + 0] = logf(1.f - pp);
    outf[2 * b + 1] = logf(pp);
    float* cp = outf + 2 * B_ + (size_t)B_ * RL_ * A_;
    cp[2 * b + 0] = 1.f - pp;
    cp[2 * b + 1] = pp;
  }
}

// ---------------- launch ----------------
extern "C" void kernel_launch(void* const* d_in, const int* in_sizes, int n_in,
                              void* d_out, int out_size, void* d_ws, size_t ws_size,
                              hipStream_t stream)
{
  const float* x     = (const float*)d_in[0];
  const int*   xmask = (const int*)d_in[1];
  const float* W1 = (const float*)d_in[2];  const float* b1 = (const float*)d_in[3];
  const float* W2 = (const float*)d_in[4];  const float* b2 = (const float*)d_in[5];
  const float* W3 = (const float*)d_in[6];  const float* b3 = (const float*)d_in[7];
  const float* Wih = (const float*)d_in[8]; const float* bih = (const float*)d_in[9];
  const float* Whh = (const float*)d_in[10];const float* bhh = (const float*)d_in[11];
  const float* Wh = (const float*)d_in[12]; const float* bh = (const float*)d_in[13];
  const float* ae = (const float*)d_in[14];
  const float* w_mu = (const float*)d_in[15];  const float* b_mu = (const float*)d_in[16];
  const float* w_cov = (const float*)d_in[17]; const float* b_cov = (const float*)d_in[18];
  const float* alpha = (const float*)d_in[19];

  char* ws = (char*)d_ws;
  size_t off = 0;
  auto alloc = [&](size_t bytes) -> void* {
    void* p = ws + off;
    off += (bytes + 255) & ~(size_t)255;
    return p;
  };
  float* cls  = (float*)alloc((size_t)B_ * H_ * 4);
  float* hbuf = (float*)alloc((size_t)B_ * H_ * 4);
  float* cur  = (float*)alloc((size_t)B_ * H_ * 4);
  const size_t gi_bytes = (size_t)B_ * 3 * H_ * 4;       // 18.9 MB
  const size_t lg_bytes = (size_t)B_ * A_ * 4;           // 41 MB
  const size_t region_bytes = (2 * gi_bytes > lg_bytes) ? 2 * gi_bytes : lg_bytes;
  float* region = (float*)alloc(region_bytes);           // gi+gh alias logits
  float* gi = region;
  float* gh = region + (size_t)B_ * 3 * H_;
  float* logits = region;
  uint8_t* mask = (uint8_t*)alloc((size_t)B_ * A_);
  int* idxs = (int*)alloc((size_t)RL_ * B_ * 4);

  float* outf  = (float*)d_out;
  float* atomp = outf + 2 * B_;

  // zero the (mostly one-hot) output once per launch
  hipMemsetAsync(d_out, 0, (size_t)out_size * sizeof(float), stream);

  mask_init<<<B_, 256, 0, stream>>>(xmask, mask);

  // base MLP -> cls  (t1=cur, t2=hbuf are dead scratch at this point)
  gemm_nt<64, 64, 16, 4, 4, 1><<<dim3(H_ / 64, B_ / 64), 256, 0, stream>>>(x,    W1, b1, cur,  B_, H_, DIN_);
  gemm_nt<64, 64, 16, 4, 4, 1><<<dim3(H_ / 64, B_ / 64), 256, 0, stream>>>(cur,  W2, b2, hbuf, B_, H_, H_);
  gemm_nt<64, 64, 16, 4, 4, 0><<<dim3(H_ / 64, B_ / 64), 256, 0, stream>>>(hbuf, W3, b3, cls,  B_, H_, H_);

  // folded keys: fold_in(key(42), j) = threefry((0,42), (0,j))
  uint32_t fk0[RL_], fk1[RL_];
  for (int j = 0; j < RL_; ++j)
    threefry2x32(0u, 42u, 0u, (uint32_t)j, &fk0[j], &fk1[j]);

  for (int j = 0; j < RL_; ++j) {
    const float* gin = (j == 0) ? cls : cur;
    gemm_nt<128, 128, 16, 8, 8, 0><<<dim3(3 * H_ / 128, B_ / 128), 256, 0, stream>>>(
        gin, Wih, bih, gi, B_, 3 * H_, H_);
    if (j > 0)
      gemm_nt<128, 128, 16, 8, 8, 0><<<dim3(3 * H_ / 128, B_ / 128), 256, 0, stream>>>(
          hbuf, Whh, bhh, gh, B_, 3 * H_, H_);
    gru_elem<<<(B_ * H_ + 255) / 256, 256, 0, stream>>>(gi, gh, bhh, hbuf, j == 0 ? 1 : 0);
    gemm_nt<128, 128, 16, 8, 8, 0><<<dim3((A_ + 127) / 128, B_ / 128), 256, 0, stream>>>(
        hbuf, Wh, bh, logits, B_, A_, H_);
    select_step<<<B_, 256, 0, stream>>>(logits, mask, idxs, cls, ae, cur, atomp,
                                        fk0[j], fk1[j], j);
  }

  head_k<<<B_, 256, 0, stream>>>(idxs, ae, w_mu, b_mu, w_cov, b_cov, alpha, outf);
}

// Round 3
// 1690.731 us; speedup vs baseline: 1.5607x; 1.5607x over previous
//
#include <hip/hip_runtime.h>
#include <stdint.h>
#include <math.h>

#define B_    2048
#define DIN_  512
#define H_    768
#define A_    5001
#define RL_   4
#define NDATA_ 56000.0f

typedef _Float16 f16x8 __attribute__((ext_vector_type(8)));
typedef _Float16 f16x4 __attribute__((ext_vector_type(4)));
typedef float    f32x4 __attribute__((ext_vector_type(4)));

// ---------------- threefry2x32 (exact JAX semantics) ----------------
__host__ __device__ __forceinline__ void threefry2x32(
    uint32_t k0, uint32_t k1, uint32_t x0, uint32_t x1,
    uint32_t* o0, uint32_t* o1)
{
  const uint32_t ks2 = k0 ^ k1 ^ 0x1BD11BDAu;
#define TF_R(r) { x0 += x1; x1 = (x1 << (r)) | (x1 >> (32 - (r))); x1 ^= x0; }
  x0 += k0; x1 += k1;
  TF_R(13) TF_R(15) TF_R(26) TF_R(6)
  x0 += k1;  x1 += ks2 + 1u;
  TF_R(17) TF_R(29) TF_R(16) TF_R(24)
  x0 += ks2; x1 += k0 + 2u;
  TF_R(13) TF_R(15) TF_R(26) TF_R(6)
  x0 += k0;  x1 += k1 + 3u;
  TF_R(17) TF_R(29) TF_R(16) TF_R(24)
  x0 += k1;  x1 += ks2 + 4u;
  TF_R(13) TF_R(15) TF_R(26) TF_R(6)
  x0 += ks2; x1 += k0 + 5u;
#undef TF_R
  *o0 = x0; *o1 = x1;
}

__device__ __forceinline__ float gumbel_for(uint32_t k0, uint32_t k1, uint32_t n)
{
  uint32_t o0, o1;
  threefry2x32(k0, k1, 0u, n, &o0, &o1);
  const uint32_t bits = o0 ^ o1;
  const float f = __uint_as_float((bits >> 9) | 0x3f800000u);  // [1,2)
  const float minv = 1e-6f;
  const float maxv = 1.0f - 1e-6f;
  const float span = maxv - minv;
  float u = __fmul_rn(f, span);
  u = __fadd_rn(u, minv);
  u = __fsub_rn(u, span);
  u = fmaxf(minv, u);
  return -logf(-logf(u));
}

// split v*64 into f16 hi/lo (by-value result: vector elements can't bind to refs)
struct HL { _Float16 h, l; };
__device__ __forceinline__ HL split64(float v)
{
  HL r;
  const float s = v * 64.f;
  r.h = (_Float16)s;
  r.l = (_Float16)(s - (float)r.h);
  return r;
}

// ---------------- fp16x3-split MFMA GEMM ----------------
// C[M,N] = A[M,K] @ W[N,K]^T + bias.  A pre-split (scaled x64) as Ahi/Alo f16.
// W is raw fp32, split in-kernel (scaled x64).  Epilogue: acc/4096 + bias.
// Block 128x128, BK=32, 4 waves each owning a 64x64 quadrant of 4x4 16x16x32 MFMAs.
template<int ACT, int WF32, int WSPLIT>
__global__ __launch_bounds__(256)
void gemm3h(const _Float16* __restrict__ Ahi, const _Float16* __restrict__ Alo,
            const float* __restrict__ Bw, const float* __restrict__ bias,
            float* __restrict__ C, _Float16* __restrict__ Chi,
            _Float16* __restrict__ Clo, int M, int N, int K)
{
  constexpr int LDK = 40;  // padded f16 row stride: 80 B, 16B-aligned, conflict-free frags
  __shared__ _Float16 sAh[128 * LDK];
  __shared__ _Float16 sAl[128 * LDK];
  __shared__ _Float16 sBh[128 * LDK];
  __shared__ _Float16 sBl[128 * LDK];

  const int tid = threadIdx.x;
  const int lane = tid & 63, wave = tid >> 6;
  const int wx = wave & 1, wy = wave >> 1;
  const int bm = blockIdx.y * 128, bn = blockIdx.x * 128;
  const int q = lane >> 4, mr = lane & 15;

  f32x4 acc[4][4];
#pragma unroll
  for (int i = 0; i < 4; ++i)
#pragma unroll
    for (int j = 0; j < 4; ++j) acc[i][j] = (f32x4)0.f;

  for (int k0 = 0; k0 < K; k0 += 32) {
    __syncthreads();
    // ---- stage A (pre-split f16, direct b128 copies) ----
#pragma unroll
    for (int it = 0; it < 4; ++it) {
      const _Float16* src = (it < 2) ? Ahi : Alo;
      _Float16* dst = (it < 2) ? sAh : sAl;
      const int pc = tid + (it & 1) * 256;        // 0..511
      const int row = pc >> 2, k8 = pc & 3;
      const f16x8 v = *(const f16x8*)(src + (size_t)(bm + row) * K + k0 + k8 * 8);
      *(f16x8*)&dst[row * LDK + k8 * 8] = v;
    }
    // ---- stage B (raw fp32 weights, scale+split in flight) ----
#pragma unroll
    for (int it = 0; it < 4; ++it) {
      const int pc = tid + it * 256;              // 0..1023
      const int row = pc >> 3, k4 = pc & 7;
      float4 w = make_float4(0.f, 0.f, 0.f, 0.f);
      if (bn + row < N)
        w = *(const float4*)(Bw + (size_t)(bn + row) * K + k0 + k4 * 4);
      const HL sx = split64(w.x), sy = split64(w.y);
      const HL sz = split64(w.z), sw = split64(w.w);
      const f16x4 h = {sx.h, sy.h, sz.h, sw.h};
      const f16x4 l = {sx.l, sy.l, sz.l, sw.l};
      *(f16x4*)&sBh[row * LDK + k4 * 4] = h;
      *(f16x4*)&sBl[row * LDK + k4 * 4] = l;
    }
    __syncthreads();

    // ---- fragments + MFMA ----
    f16x8 ah[4], al[4];
    const int abase = (wy * 64 + mr) * LDK + q * 8;
#pragma unroll
    for (int mi = 0; mi < 4; ++mi) {
      ah[mi] = *(const f16x8*)&sAh[abase + mi * 16 * LDK];
      al[mi] = *(const f16x8*)&sAl[abase + mi * 16 * LDK];
    }
    const int bbase = (wx * 64 + mr) * LDK + q * 8;
#pragma unroll
    for (int ni = 0; ni < 4; ++ni) {
      const f16x8 bh = *(const f16x8*)&sBh[bbase + ni * 16 * LDK];
      const f16x8 bl = *(const f16x8*)&sBl[bbase + ni * 16 * LDK];
#pragma unroll
      for (int mi = 0; mi < 4; ++mi) {
        acc[mi][ni] = __builtin_amdgcn_mfma_f32_16x16x32_f16(ah[mi], bh, acc[mi][ni], 0, 0, 0);
        acc[mi][ni] = __builtin_amdgcn_mfma_f32_16x16x32_f16(al[mi], bh, acc[mi][ni], 0, 0, 0);
        acc[mi][ni] = __builtin_amdgcn_mfma_f32_16x16x32_f16(ah[mi], bl, acc[mi][ni], 0, 0, 0);
      }
    }
  }

  // ---- epilogue: C/D layout col=lane&15, row=(lane>>4)*4+reg ----
  const float sc = 1.f / 4096.f;
#pragma unroll
  for (int ni = 0; ni < 4; ++ni) {
    const int n = bn + wx * 64 + ni * 16 + mr;
    if (n >= N) continue;
    const float bv = bias[n];
#pragma unroll
    for (int mi = 0; mi < 4; ++mi) {
      const int m0 = bm + wy * 64 + mi * 16 + q * 4;
#pragma unroll
      for (int r = 0; r < 4; ++r) {
        float v = acc[mi][ni][r] * sc + bv;
        if (ACT) v = fmaxf(v, 0.f);
        const size_t off = (size_t)(m0 + r) * N + n;
        if (WF32) C[off] = v;
        if (WSPLIT) {
          const HL s = split64(v);
          Chi[off] = s.h;
          Clo[off] = s.l;
        }
      }
    }
  }
}

// ---------------- split x (scaled x64) ----------------
__global__ __launch_bounds__(256)
void split4_k(const float* __restrict__ src, _Float16* __restrict__ hi,
              _Float16* __restrict__ lo, int n4)
{
  const int i = blockIdx.x * 256 + threadIdx.x;
  if (i >= n4) return;
  const float4 f = ((const float4*)src)[i];
  const HL s0 = split64(f.x), s1 = split64(f.y);
  const HL s2 = split64(f.z), s3 = split64(f.w);
  const f16x4 hv = {s0.h, s1.h, s2.h, s3.h};
  const f16x4 lv = {s0.l, s1.l, s2.l, s3.l};
  ((f16x4*)hi)[i] = hv;
  ((f16x4*)lo)[i] = lv;
}

// ---------------- mask init (+ step-0 row_zero fix) ----------------
__global__ __launch_bounds__(256)
void mask_init(const int* __restrict__ xmask, uint8_t* __restrict__ mask)
{
  const int b = blockIdx.x, tid = threadIdx.x;
  int s = 0;
  for (int a = tid; a < A_; a += 256) {
    const int m = (xmask[(size_t)b * A_ + a] != 0) ? 1 : 0;
    mask[(size_t)b * A_ + a] = (uint8_t)m;
    s += m;
  }
  __shared__ int red[256];
  red[tid] = s; __syncthreads();
  for (int t = 128; t > 0; t >>= 1) {
    if (tid < t) red[tid] += red[tid + t];
    __syncthreads();
  }
  if (tid == 0 && red[0] == 0) mask[(size_t)b * A_] = 1;
}

// ---------------- GRU elementwise + fused h split ----------------
__global__ __launch_bounds__(256)
void gru_elem(const float* __restrict__ gi, const float* __restrict__ gh,
              const float* __restrict__ bhh, float* __restrict__ h,
              _Float16* __restrict__ hh_, _Float16* __restrict__ hl_, int first)
{
  const int i = blockIdx.x * 256 + threadIdx.x;
  if (i >= B_ * H_) return;
  const int b = i / H_;
  const int d = i - b * H_;
  const float* gib = gi + (size_t)b * 3 * H_;
  const float ir = gib[d], iz = gib[H_ + d], in_ = gib[2 * H_ + d];
  float hr, hz, hn, hp;
  if (first) {            // h == 0 -> gh = b_hh exactly (saves a full GEMM)
    hr = bhh[d]; hz = bhh[H_ + d]; hn = bhh[2 * H_ + d]; hp = 0.f;
  } else {
    const float* ghb = gh + (size_t)b * 3 * H_;
    hr = ghb[d]; hz = ghb[H_ + d]; hn = ghb[2 * H_ + d]; hp = h[i];
  }
  const float r = 1.f / (1.f + expf(-(ir + hr)));
  const float z = 1.f / (1.f + expf(-(iz + hz)));
  const float n = tanhf(in_ + r * hn);
  const float hv = (1.f - z) * n + z * hp;
  h[i] = hv;
  const HL s = split64(hv);
  hh_[i] = s.h; hl_[i] = s.l;
}

// ---------------- per-step masked gumbel argmax + mask/cur update ----------
__global__ __launch_bounds__(256)
void select_step(const float* __restrict__ logits, uint8_t* __restrict__ mask,
                 int* __restrict__ idxs, const float* __restrict__ cls,
                 const float* __restrict__ ae, _Float16* __restrict__ curh,
                 _Float16* __restrict__ curl, float* __restrict__ atomp,
                 uint32_t k0, uint32_t k1, int step)
{
  const int b = blockIdx.x, tid = threadIdx.x;
  uint8_t* mrow = mask + (size_t)b * A_;

  if (step > 0) {
    const int prev = idxs[(step - 1) * B_ + b];
    if (prev == 0) {
      for (int a = tid; a < A_; a += 256) mrow[a] = 0;
    }
    __syncthreads();
    if (tid == 0) mrow[0] = 1;
    __syncthreads();
  }

  const float* lrow = logits + (size_t)b * A_;
  const uint32_t nbase = (uint32_t)b * (uint32_t)A_;
  float bv = -INFINITY;
  int bi = A_;
  for (int a = tid; a < A_; a += 256) {
    if (mrow[a]) {
      const float v = lrow[a] + gumbel_for(k0, k1, nbase + (uint32_t)a);
      if (v > bv) { bv = v; bi = a; }   // strictly >, a increasing -> first-max kept
    }
  }
  __shared__ float sv[256];
  __shared__ int   si[256];
  sv[tid] = bv; si[tid] = bi;
  __syncthreads();
  for (int s = 128; s > 0; s >>= 1) {
    if (tid < s) {
      const float v2 = sv[tid + s]; const int i2 = si[tid + s];
      if (v2 > sv[tid] || (v2 == sv[tid] && i2 < si[tid])) { sv[tid] = v2; si[tid] = i2; }
    }
    __syncthreads();
  }
  const int sel = si[0];
  if (tid == 0) {
    mrow[sel] = 0;
    idxs[step * B_ + b] = sel;
    atomp[(size_t)b * (RL_ * A_) + (size_t)step * A_ + sel] = 1.0f;
  }
  const float* aerow = ae + (size_t)sel * H_;
  const float* clsr  = cls + (size_t)b * H_;
  for (int d = tid; d < H_; d += 256) {
    const float c = clsr[d] + aerow[d];
    const HL s = split64(c);
    curh[(size_t)b * H_ + d] = s.h;
    curl[(size_t)b * H_ + d] = s.l;
  }
}

// ---------------- final heads ----------------
__global__ __launch_bounds__(256)
void head_k(const int* __restrict__ idxs, const float* __restrict__ ae,
            const float* __restrict__ w_mu, const float* __restrict__ b_mu,
            const float* __restrict__ w_cov, const float* __restrict__ b_cov,
            const float* __restrict__ alpha, float* __restrict__ outf)
{
  const int b = blockIdx.x, tid = threadIdx.x;
  const int i0 = idxs[0 * B_ + b], i1 = idxs[1 * B_ + b];
  const int i2 = idxs[2 * B_ + b], i3 = idxs[3 * B_ + b];
  const float* r0 = ae + (size_t)i0 * H_;
  const float* r1 = ae + (size_t)i1 * H_;
  const float* r2 = ae + (size_t)i2 * H_;
  const float* r3 = ae + (size_t)i3 * H_;
  float pmu = 0.f, pcv = 0.f;
  for (int d = tid; d < H_; d += 256) {
    const float a = r0[d] + r1[d] + r2[d] + r3[d];
    pmu += a * w_mu[d];
    pcv += a * w_cov[d];
  }
  __shared__ float smu[256], scv[256];
  smu[tid] = pmu; scv[tid] = pcv;
  __syncthreads();
  for (int s = 128; s > 0; s >>= 1) {
    if (tid < s) { smu[tid] += smu[tid + s]; scv[tid] += scv[tid + s]; }
    __syncthreads();
  }
  if (tid == 0) {
    const float mu = 1.f / (1.f + expf(-(smu[0] + b_mu[0])));
    const float cv = 1.f / (1.f + expf(-(scv[0] + b_cov[0])));
    const float n = cv * NDATA_;
    const float inv = alpha[0] / n;
    const float pp = (mu + inv) / (1.f + 2.f * inv);
    outf[2 * b + 0] = logf(1.f - pp);
    outf[2 * b + 1] = logf(pp);
    float* cp = outf + 2 * B_ + (size_t)B_ * RL_ * A_;
    cp[2 * b + 0] = 1.f - pp;
    cp[2 * b + 1] = pp;
  }
}

// ---------------- launch ----------------
extern "C" void kernel_launch(void* const* d_in, const int* in_sizes, int n_in,
                              void* d_out, int out_size, void* d_ws, size_t ws_size,
                              hipStream_t stream)
{
  const float* x     = (const float*)d_in[0];
  const int*   xmask = (const int*)d_in[1];
  const float* W1 = (const float*)d_in[2];  const float* b1 = (const float*)d_in[3];
  const float* W2 = (const float*)d_in[4];  const float* b2 = (const float*)d_in[5];
  const float* W3 = (const float*)d_in[6];  const float* b3 = (const float*)d_in[7];
  const float* Wih = (const float*)d_in[8]; const float* bih = (const float*)d_in[9];
  const float* Whh = (const float*)d_in[10];const float* bhh = (const float*)d_in[11];
  const float* Wh = (const float*)d_in[12]; const float* bh = (const float*)d_in[13];
  const float* ae = (const float*)d_in[14];
  const float* w_mu = (const float*)d_in[15];  const float* b_mu = (const float*)d_in[16];
  const float* w_cov = (const float*)d_in[17]; const float* b_cov = (const float*)d_in[18];
  const float* alpha = (const float*)d_in[19];

  char* ws = (char*)d_ws;
  size_t off = 0;
  auto alloc = [&](size_t bytes) -> void* {
    void* p = ws + off;
    off += (bytes + 255) & ~(size_t)255;
    return p;
  };
  float* cls  = (float*)alloc((size_t)B_ * H_ * 4);
  float* hbuf = (float*)alloc((size_t)B_ * H_ * 4);
  const size_t gi_bytes = (size_t)B_ * 3 * H_ * 4;       // 18.9 MB
  const size_t lg_bytes = (size_t)B_ * A_ * 4;           // 41 MB
  const size_t region_bytes = (2 * gi_bytes > lg_bytes) ? 2 * gi_bytes : lg_bytes;
  char* region = (char*)alloc(region_bytes);             // gi+gh alias logits alias x/t splits
  float* gi = (float*)region;
  float* gh = (float*)(region + gi_bytes);
  float* logits = (float*)region;
  // MLP-phase split buffers carved inside region (dead before gi is written)
  _Float16* xh  = (_Float16*)region;
  _Float16* xl  = xh + (size_t)B_ * DIN_;
  _Float16* t1h = xl + (size_t)B_ * DIN_;
  _Float16* t1l = t1h + (size_t)B_ * H_;
  _Float16* t2h = t1l + (size_t)B_ * H_;
  _Float16* t2l = t2h + (size_t)B_ * H_;
  uint8_t* mask = (uint8_t*)alloc((size_t)B_ * A_);
  int* idxs = (int*)alloc((size_t)RL_ * B_ * 4);
  _Float16* clsh = (_Float16*)alloc((size_t)B_ * H_ * 2);
  _Float16* clsl = (_Float16*)alloc((size_t)B_ * H_ * 2);
  _Float16* hh_  = (_Float16*)alloc((size_t)B_ * H_ * 2);
  _Float16* hl_  = (_Float16*)alloc((size_t)B_ * H_ * 2);
  _Float16* curh = (_Float16*)alloc((size_t)B_ * H_ * 2);
  _Float16* curl = (_Float16*)alloc((size_t)B_ * H_ * 2);

  float* outf  = (float*)d_out;
  float* atomp = outf + 2 * B_;

  (void)hipMemsetAsync(d_out, 0, (size_t)out_size * sizeof(float), stream);

  mask_init<<<B_, 256, 0, stream>>>(xmask, mask);
  split4_k<<<(B_ * DIN_ / 4 + 255) / 256, 256, 0, stream>>>(x, xh, xl, B_ * DIN_ / 4);

  // base MLP: x -> t1 -> t2 -> cls   (split-only intermediates; cls gets fp32 + split)
  gemm3h<1, 0, 1><<<dim3(H_ / 128, B_ / 128), 256, 0, stream>>>(
      xh, xl, W1, b1, nullptr, t1h, t1l, B_, H_, DIN_);
  gemm3h<1, 0, 1><<<dim3(H_ / 128, B_ / 128), 256, 0, stream>>>(
      t1h, t1l, W2, b2, nullptr, t2h, t2l, B_, H_, H_);
  gemm3h<0, 1, 1><<<dim3(H_ / 128, B_ / 128), 256, 0, stream>>>(
      t2h, t2l, W3, b3, cls, clsh, clsl, B_, H_, H_);

  // folded keys: fold_in(key(42), j) = threefry((0,42), (0,j))
  uint32_t fk0[RL_], fk1[RL_];
  for (int j = 0; j < RL_; ++j)
    threefry2x32(0u, 42u, 0u, (uint32_t)j, &fk0[j], &fk1[j]);

  for (int j = 0; j < RL_; ++j) {
    const _Float16* ginh = (j == 0) ? clsh : curh;
    const _Float16* ginl = (j == 0) ? clsl : curl;
    gemm3h<0, 1, 0><<<dim3(3 * H_ / 128, B_ / 128), 256, 0, stream>>>(
        ginh, ginl, Wih, bih, gi, nullptr, nullptr, B_, 3 * H_, H_);
    if (j > 0)
      gemm3h<0, 1, 0><<<dim3(3 * H_ / 128, B_ / 128), 256, 0, stream>>>(
          hh_, hl_, Whh, bhh, gh, nullptr, nullptr, B_, 3 * H_, H_);
    gru_elem<<<(B_ * H_ + 255) / 256, 256, 0, stream>>>(gi, gh, bhh, hbuf, hh_, hl_,
                                                        j == 0 ? 1 : 0);
    gemm3h<0, 1, 0><<<dim3((A_ + 127) / 128, B_ / 128), 256, 0, stream>>>(
        hh_, hl_, Wh, bh, logits, nullptr, nullptr, B_, A_, H_);
    select_step<<<B_, 256, 0, stream>>>(logits, mask, idxs, cls, ae, curh, curl,
                                        atomp, fk0[j], fk1[j], j);
  }

  head_k<<<B_, 256, 0, stream>>>(idxs, ae, w_mu, b_mu, w_cov, b_cov, alpha, outf);
}

// Round 4
// 1216.371 us; speedup vs baseline: 2.1693x; 1.3900x over previous
//
#include <hip/hip_runtime.h>
#include <stdint.h>
#include <math.h>

#define B_    2048
#define DIN_  512
#define H_    768
#define A_    5001
#define APAD_ 5120
#define RL_   4
#define NDATA_ 56000.0f

typedef _Float16 f16x8 __attribute__((ext_vector_type(8)));
typedef _Float16 f16x4 __attribute__((ext_vector_type(4)));
typedef float    f32x4 __attribute__((ext_vector_type(4)));

// ---------------- threefry2x32 (exact JAX semantics) ----------------
__host__ __device__ __forceinline__ void threefry2x32(
    uint32_t k0, uint32_t k1, uint32_t x0, uint32_t x1,
    uint32_t* o0, uint32_t* o1)
{
  const uint32_t ks2 = k0 ^ k1 ^ 0x1BD11BDAu;
#define TF_R(r) { x0 += x1; x1 = (x1 << (r)) | (x1 >> (32 - (r))); x1 ^= x0; }
  x0 += k0; x1 += k1;
  TF_R(13) TF_R(15) TF_R(26) TF_R(6)
  x0 += k1;  x1 += ks2 + 1u;
  TF_R(17) TF_R(29) TF_R(16) TF_R(24)
  x0 += ks2; x1 += k0 + 2u;
  TF_R(13) TF_R(15) TF_R(26) TF_R(6)
  x0 += k0;  x1 += k1 + 3u;
  TF_R(17) TF_R(29) TF_R(16) TF_R(24)
  x0 += k1;  x1 += ks2 + 4u;
  TF_R(13) TF_R(15) TF_R(26) TF_R(6)
  x0 += ks2; x1 += k0 + 5u;
#undef TF_R
  *o0 = x0; *o1 = x1;
}

__device__ __forceinline__ float gumbel_for(uint32_t k0, uint32_t k1, uint32_t n)
{
  uint32_t o0, o1;
  threefry2x32(k0, k1, 0u, n, &o0, &o1);
  const uint32_t bits = o0 ^ o1;
  const float f = __uint_as_float((bits >> 9) | 0x3f800000u);  // [1,2)
  const float minv = 1e-6f;
  const float maxv = 1.0f - 1e-6f;
  const float span = maxv - minv;
  float u = __fmul_rn(f, span);
  u = __fadd_rn(u, minv);
  u = __fsub_rn(u, span);
  u = fmaxf(minv, u);
  return -logf(-logf(u));
}

// split v*64 into f16 hi/lo
struct HL { _Float16 h, l; };
__device__ __forceinline__ HL split64(float v)
{
  HL r;
  const float s = v * 64.f;
  r.h = (_Float16)s;
  r.l = (_Float16)(s - (float)r.h);
  return r;
}

// async global->LDS, 16 B per lane; LDS dst = base + lane*16 (wave-uniform base)
__device__ __forceinline__ void gload16(const void* g, void* l)
{
  __builtin_amdgcn_global_load_lds(
      (const __attribute__((address_space(1))) void*)g,
      (__attribute__((address_space(3))) void*)l, 16, 0, 0);
}

// ---------------- pre-split weights: fp32 [R][K] -> f16 hi/lo [Rpad][K] ----
__global__ __launch_bounds__(256)
void presplit(const float* __restrict__ src, _Float16* __restrict__ hi,
              _Float16* __restrict__ lo, int R, int Rpad, int K)
{
  const int n4 = Rpad * K / 4;
  const int i = blockIdx.x * 256 + threadIdx.x;
  if (i >= n4) return;
  const int e = i * 4;
  const int row = e / K;
  float4 f = make_float4(0.f, 0.f, 0.f, 0.f);
  if (row < R) f = *(const float4*)(src + (size_t)row * K + (e - row * K));
  const HL s0 = split64(f.x), s1 = split64(f.y);
  const HL s2 = split64(f.z), s3 = split64(f.w);
  const f16x4 hv = {s0.h, s1.h, s2.h, s3.h};
  ((f16x4*)hi)[i] = hv;
  if (lo) {
    const f16x4 lv = {s0.l, s1.l, s2.l, s3.l};
    ((f16x4*)lo)[i] = lv;
  }
}

// ---------------- max ||Wh_a||^2 (for the refine bound) ----------------
__global__ __launch_bounds__(256)
void wmax_k(const float* __restrict__ Wh, float* __restrict__ wmaxsq)
{
  const int a = blockIdx.x, tid = threadIdx.x;
  float p = 0.f;
  for (int d = tid; d < H_; d += 256) {
    const float w = Wh[(size_t)a * H_ + d];
    p += w * w;
  }
  __shared__ float red[256];
  red[tid] = p; __syncthreads();
  for (int t = 128; t > 0; t >>= 1) {
    if (tid < t) red[tid] += red[tid + t];
    __syncthreads();
  }
  if (tid == 0) atomicMax((int*)wmaxsq, __float_as_int(red[0]));
}

// ---------------- f16-split MFMA GEMM, global_load_lds staging ----------
// C[M,N] = A @ B^T (both pre-split, scaled x64; epilogue /4096 + bias).
// NPASS=3: hi*hi + lo*hi + hi*lo (fp32-class).  NPASS=1: hi*hi (approx).
// Block 128x128, BK=32, 4 waves each own a 64x64 quadrant (4x4 of 16x16x32).
template<int ACT, int WF32, int WSPLIT, int NPASS>
__global__ __launch_bounds__(256)
void gemmA(const _Float16* __restrict__ Ahi, const _Float16* __restrict__ Alo,
           const _Float16* __restrict__ Bhi, const _Float16* __restrict__ Blo,
           const float* __restrict__ bias, float* __restrict__ C,
           _Float16* __restrict__ Chi, _Float16* __restrict__ Clo,
           int M, int N, int K)
{
  constexpr int NSP = (NPASS == 3) ? 2 : 1;
  __shared__ _Float16 sA[NSP][128 * 32];   // [rows 128][k 32], unpadded (DMA layout)
  __shared__ _Float16 sB[NSP][128 * 32];

  const int tid = threadIdx.x;
  const int lane = tid & 63, wave = tid >> 6;
  const int wx = wave & 1, wy = wave >> 1;
  const int bm = blockIdx.y * 128, bn = blockIdx.x * 128;
  const int q = lane >> 4, mr = lane & 15;

  f32x4 acc[4][4];
#pragma unroll
  for (int i = 0; i < 4; ++i)
#pragma unroll
    for (int j = 0; j < 4; ++j) acc[i][j] = (f32x4)0.f;

  for (int k0 = 0; k0 < K; k0 += 32) {
    __syncthreads();
    // stage: each wave DMAs 2 chunks (16 rows x 32 f16 = 1 KB) per tile
#pragma unroll
    for (int t = 0; t < 2; ++t) {
      const int c = wave * 2 + t;                 // chunk 0..7
      const int row = c * 16 + (lane >> 2);
      const int kc = (lane & 3) * 8;
      const size_t ga = (size_t)(bm + row) * K + k0 + kc;
      const size_t gb = (size_t)(bn + row) * K + k0 + kc;
      gload16(Ahi + ga, &sA[0][c * 512]);
      gload16(Bhi + gb, &sB[0][c * 512]);
      if constexpr (NPASS == 3) {
        gload16(Alo + ga, &sA[1][c * 512]);
        gload16(Blo + gb, &sB[1][c * 512]);
      }
    }
    __syncthreads();

    f16x8 ah[4], al[4];
    const int abase = (wy * 64 + mr) * 32 + q * 8;
#pragma unroll
    for (int mi = 0; mi < 4; ++mi) {
      ah[mi] = *(const f16x8*)&sA[0][abase + mi * 16 * 32];
      if constexpr (NPASS == 3)
        al[mi] = *(const f16x8*)&sA[1][abase + mi * 16 * 32];
    }
    const int bbase = (wx * 64 + mr) * 32 + q * 8;
#pragma unroll
    for (int ni = 0; ni < 4; ++ni) {
      const f16x8 bh = *(const f16x8*)&sB[0][bbase + ni * 16 * 32];
      if constexpr (NPASS == 3) {
        const f16x8 bl = *(const f16x8*)&sB[1][bbase + ni * 16 * 32];
#pragma unroll
        for (int mi = 0; mi < 4; ++mi) {
          acc[mi][ni] = __builtin_amdgcn_mfma_f32_16x16x32_f16(ah[mi], bh, acc[mi][ni], 0, 0, 0);
          acc[mi][ni] = __builtin_amdgcn_mfma_f32_16x16x32_f16(al[mi], bh, acc[mi][ni], 0, 0, 0);
          acc[mi][ni] = __builtin_amdgcn_mfma_f32_16x16x32_f16(ah[mi], bl, acc[mi][ni], 0, 0, 0);
        }
      } else {
#pragma unroll
        for (int mi = 0; mi < 4; ++mi)
          acc[mi][ni] = __builtin_amdgcn_mfma_f32_16x16x32_f16(ah[mi], bh, acc[mi][ni], 0, 0, 0);
      }
    }
  }

  // epilogue: C/D layout col=lane&15, row=(lane>>4)*4+reg
  const float sc = 1.f / 4096.f;
#pragma unroll
  for (int ni = 0; ni < 4; ++ni) {
    const int n = bn + wx * 64 + ni * 16 + mr;
    if (n >= N) continue;
    const float bv = bias[n];
#pragma unroll
    for (int mi = 0; mi < 4; ++mi) {
      const int m0 = bm + wy * 64 + mi * 16 + q * 4;
#pragma unroll
      for (int r = 0; r < 4; ++r) {
        float v = acc[mi][ni][r] * sc + bv;
        if (ACT) v = fmaxf(v, 0.f);
        const size_t off = (size_t)(m0 + r) * N + n;
        if (WF32) C[off] = v;
        if (WSPLIT) {
          const HL s = split64(v);
          Chi[off] = s.h;
          Clo[off] = s.l;
        }
      }
    }
  }
}

// ---------------- split x (scaled x64) ----------------
__global__ __launch_bounds__(256)
void split4_k(const float* __restrict__ src, _Float16* __restrict__ hi,
              _Float16* __restrict__ lo, int n4)
{
  const int i = blockIdx.x * 256 + threadIdx.x;
  if (i >= n4) return;
  const float4 f = ((const float4*)src)[i];
  const HL s0 = split64(f.x), s1 = split64(f.y);
  const HL s2 = split64(f.z), s3 = split64(f.w);
  const f16x4 hv = {s0.h, s1.h, s2.h, s3.h};
  const f16x4 lv = {s0.l, s1.l, s2.l, s3.l};
  ((f16x4*)hi)[i] = hv;
  ((f16x4*)lo)[i] = lv;
}

// ---------------- mask init (+ step-0 row_zero fix) ----------------
__global__ __launch_bounds__(256)
void mask_init(const int* __restrict__ xmask, uint8_t* __restrict__ mask)
{
  const int b = blockIdx.x, tid = threadIdx.x;
  int s = 0;
  for (int a = tid; a < A_; a += 256) {
    const int m = (xmask[(size_t)b * A_ + a] != 0) ? 1 : 0;
    mask[(size_t)b * A_ + a] = (uint8_t)m;
    s += m;
  }
  __shared__ int red[256];
  red[tid] = s; __syncthreads();
  for (int t = 128; t > 0; t >>= 1) {
    if (tid < t) red[tid] += red[tid + t];
    __syncthreads();
  }
  if (tid == 0 && red[0] == 0) mask[(size_t)b * A_] = 1;
}

// ---------------- GRU elementwise + fused h split ----------------
__global__ __launch_bounds__(256)
void gru_elem(const float* __restrict__ gi, const float* __restrict__ gh,
              const float* __restrict__ bhh, float* __restrict__ h,
              _Float16* __restrict__ hh_, _Float16* __restrict__ hl_, int first)
{
  const int i = blockIdx.x * 256 + threadIdx.x;
  if (i >= B_ * H_) return;
  const int b = i / H_;
  const int d = i - b * H_;
  const float* gib = gi + (size_t)b * 3 * H_;
  const float ir = gib[d], iz = gib[H_ + d], in_ = gib[2 * H_ + d];
  float hr, hz, hn, hp;
  if (first) {            // h == 0 -> gh = b_hh exactly (saves a full GEMM)
    hr = bhh[d]; hz = bhh[H_ + d]; hn = bhh[2 * H_ + d]; hp = 0.f;
  } else {
    const float* ghb = gh + (size_t)b * 3 * H_;
    hr = ghb[d]; hz = ghb[H_ + d]; hn = ghb[2 * H_ + d]; hp = h[i];
  }
  const float r = 1.f / (1.f + expf(-(ir + hr)));
  const float z = 1.f / (1.f + expf(-(iz + hz)));
  const float n = tanhf(in_ + r * hn);
  const float hv = (1.f - z) * n + z * hp;
  h[i] = hv;
  const HL s = split64(hv);
  hh_[i] = s.h; hl_[i] = s.l;
}

// ---------------- select: approx argmax + sound exact refine ----------
__global__ __launch_bounds__(256)
void select_step(const float* __restrict__ logits, uint8_t* __restrict__ mask,
                 int* __restrict__ idxs, const float* __restrict__ cls,
                 const float* __restrict__ ae, _Float16* __restrict__ curh,
                 _Float16* __restrict__ curl, float* __restrict__ atomp,
                 const float* __restrict__ hbuf, const float* __restrict__ WhF,
                 const float* __restrict__ bh, const float* __restrict__ wmaxsq,
                 uint32_t k0, uint32_t k1, int step)
{
  const int b = blockIdx.x, tid = threadIdx.x;
  uint8_t* mrow = mask + (size_t)b * A_;
  __shared__ float hsh[H_];
  __shared__ float sv[256];
  __shared__ int   si[256];
  __shared__ int   s_list[256];
  __shared__ int   s_n;
  __shared__ int   s_sel;

  // h row -> LDS + ||h||^2
  float hp = 0.f;
  for (int d = tid; d < H_; d += 256) {
    const float v = hbuf[(size_t)b * H_ + d];
    hsh[d] = v; hp += v * v;
  }
  sv[tid] = hp; __syncthreads();
  for (int t = 128; t > 0; t >>= 1) {
    if (tid < t) sv[tid] += sv[tid + t];
    __syncthreads();
  }
  const float hn2 = sv[0];
  __syncthreads();

  // mask update
  if (step > 0) {
    const int prev = idxs[(step - 1) * B_ + b];
    if (prev == 0)
      for (int a = tid; a < A_; a += 256) mrow[a] = 0;
    __syncthreads();
    if (tid == 0) mrow[0] = 1;
  }
  if (tid == 0) s_n = 0;
  __syncthreads();

  // approx max of (logit_approx + gumbel) over allowed atoms
  const uint32_t nbase = (uint32_t)b * (uint32_t)A_;
  const float* lrow = logits + (size_t)b * A_;
  float bv = -INFINITY; int bi = A_;
  for (int a = tid; a < A_; a += 256) if (mrow[a]) {
    const float v = lrow[a] + gumbel_for(k0, k1, nbase + (uint32_t)a);
    if (v > bv) { bv = v; bi = a; }
  }
  sv[tid] = bv; si[tid] = bi; __syncthreads();
  for (int t = 128; t > 0; t >>= 1) {
    if (tid < t) {
      const float v2 = sv[tid + t]; const int i2 = si[tid + t];
      if (v2 > sv[tid] || (v2 == sv[tid] && i2 < si[tid])) { sv[tid] = v2; si[tid] = i2; }
    }
    __syncthreads();
  }
  const float amax = sv[0];
  __syncthreads();

  // error bound: |approx-exact| <= 2^-10 * ||h|| * max||w_a||  (x2 safety)
  const float delta = 2.0f * 0.0009765625f * sqrtf(hn2 * wmaxsq[0]);
  const float thr = amax - 2.f * delta;

  // collect candidates within the window
  for (int a = tid; a < A_; a += 256) if (mrow[a]) {
    const float v = lrow[a] + gumbel_for(k0, k1, nbase + (uint32_t)a);
    if (v >= thr) {
      const int p = atomicAdd(&s_n, 1);
      if (p < 256) s_list[p] = a;
    }
  }
  __syncthreads();
  const int nc = (s_n < 256) ? s_n : 256;

  // exact fp32 re-eval of candidates; argmax with lowest-index tie-break
  float best = -INFINITY; int bestA = A_;    // thread0's copy is authoritative
  for (int c = 0; c < nc; ++c) {
    const int a = s_list[c];
    const float* wr = WhF + (size_t)a * H_;
    float p = 0.f;
    for (int d = tid; d < H_; d += 256) p += hsh[d] * wr[d];
    sv[tid] = p; __syncthreads();
    for (int t = 128; t > 0; t >>= 1) {
      if (tid < t) sv[tid] += sv[tid + t];
      __syncthreads();
    }
    if (tid == 0) {
      const float ev = sv[0] + bh[a] + gumbel_for(k0, k1, nbase + (uint32_t)a);
      if (ev > best || (ev == best && a < bestA)) { best = ev; bestA = a; }
    }
    __syncthreads();
  }
  if (tid == 0) {
    s_sel = bestA;
    mrow[bestA] = 0;
    idxs[step * B_ + b] = bestA;
    atomp[(size_t)b * (RL_ * A_) + (size_t)step * A_ + bestA] = 1.0f;
  }
  __syncthreads();
  const int sel = s_sel;
  const float* aerow = ae + (size_t)sel * H_;
  const float* clsr  = cls + (size_t)b * H_;
  for (int d = tid; d < H_; d += 256) {
    const float c = clsr[d] + aerow[d];
    const HL s = split64(c);
    curh[(size_t)b * H_ + d] = s.h;
    curl[(size_t)b * H_ + d] = s.l;
  }
}

// ---------------- final heads ----------------
__global__ __launch_bounds__(256)
void head_k(const int* __restrict__ idxs, const float* __restrict__ ae,
            const float* __restrict__ w_mu, const float* __restrict__ b_mu,
            const float* __restrict__ w_cov, const float* __restrict__ b_cov,
            const float* __restrict__ alpha, float* __restrict__ outf)
{
  const int b = blockIdx.x, tid = threadIdx.x;
  const int i0 = idxs[0 * B_ + b], i1 = idxs[1 * B_ + b];
  const int i2 = idxs[2 * B_ + b], i3 = idxs[3 * B_ + b];
  const float* r0 = ae + (size_t)i0 * H_;
  const float* r1 = ae + (size_t)i1 * H_;
  const float* r2 = ae + (size_t)i2 * H_;
  const float* r3 = ae + (size_t)i3 * H_;
  float pmu = 0.f, pcv = 0.f;
  for (int d = tid; d < H_; d += 256) {
    const float a = r0[d] + r1[d] + r2[d] + r3[d];
    pmu += a * w_mu[d];
    pcv += a * w_cov[d];
  }
  __shared__ float smu[256], scv[256];
  smu[tid] = pmu; scv[tid] = pcv;
  __syncthreads();
  for (int s = 128; s > 0; s >>= 1) {
    if (tid < s) { smu[tid] += smu[tid + s]; scv[tid] += scv[tid + s]; }
    __syncthreads();
  }
  if (tid == 0) {
    const float mu = 1.f / (1.f + expf(-(smu[0] + b_mu[0])));
    const float cv = 1.f / (1.f + expf(-(scv[0] + b_cov[0])));
    const float n = cv * NDATA_;
    const float inv = alpha[0] / n;
    const float pp = (mu + inv) / (1.f + 2.f * inv);
    outf[2 * b + 0] = logf(1.f - pp);
    outf[2 * b + 1] = logf(pp);
    float* cp = outf + 2 * B_ + (size_t)B_ * RL_ * A_;
    cp[2 * b + 0] = 1.f - pp;
    cp[2 * b + 1] = pp;
  }
}

// ---------------- launch ----------------
extern "C" void kernel_launch(void* const* d_in, const int* in_sizes, int n_in,
                              void* d_out, int out_size, void* d_ws, size_t ws_size,
                              hipStream_t stream)
{
  const float* x     = (const float*)d_in[0];
  const int*   xmask = (const int*)d_in[1];
  const float* W1 = (const float*)d_in[2];  const float* b1 = (const float*)d_in[3];
  const float* W2 = (const float*)d_in[4];  const float* b2 = (const float*)d_in[5];
  const float* W3 = (const float*)d_in[6];  const float* b3 = (const float*)d_in[7];
  const float* Wih = (const float*)d_in[8]; const float* bih = (const float*)d_in[9];
  const float* Whh = (const float*)d_in[10];const float* bhh = (const float*)d_in[11];
  const float* Wh = (const float*)d_in[12]; const float* bh = (const float*)d_in[13];
  const float* ae = (const float*)d_in[14];
  const float* w_mu = (const float*)d_in[15];  const float* b_mu = (const float*)d_in[16];
  const float* w_cov = (const float*)d_in[17]; const float* b_cov = (const float*)d_in[18];
  const float* alpha = (const float*)d_in[19];

  char* ws = (char*)d_ws;
  size_t off = 0;
  auto alloc = [&](size_t bytes) -> void* {
    void* p = ws + off;
    off += (bytes + 255) & ~(size_t)255;
    return p;
  };
  float* cls  = (float*)alloc((size_t)B_ * H_ * 4);
  float* hbuf = (float*)alloc((size_t)B_ * H_ * 4);
  const size_t gi_bytes = (size_t)B_ * 3 * H_ * 4;       // 18.9 MB
  const size_t lg_bytes = (size_t)B_ * A_ * 4;           // 41 MB
  const size_t region_bytes = (2 * gi_bytes > lg_bytes) ? 2 * gi_bytes : lg_bytes;
  char* region = (char*)alloc(region_bytes);             // gi+gh alias logits alias x/t splits
  float* gi = (float*)region;
  float* gh = (float*)(region + gi_bytes);
  float* logits = (float*)region;
  _Float16* xh  = (_Float16*)region;                     // MLP-phase aliases
  _Float16* xl  = xh + (size_t)B_ * DIN_;
  _Float16* t1h = xl + (size_t)B_ * DIN_;
  _Float16* t1l = t1h + (size_t)B_ * H_;
  _Float16* t2h = t1l + (size_t)B_ * H_;
  _Float16* t2l = t2h + (size_t)B_ * H_;
  uint8_t* mask = (uint8_t*)alloc((size_t)B_ * A_);
  int* idxs = (int*)alloc((size_t)RL_ * B_ * 4);
  _Float16* curh = (_Float16*)alloc((size_t)B_ * H_ * 2);  // holds cls-split at j=0
  _Float16* curl = (_Float16*)alloc((size_t)B_ * H_ * 2);
  _Float16* hh_  = (_Float16*)alloc((size_t)B_ * H_ * 2);
  _Float16* hl_  = (_Float16*)alloc((size_t)B_ * H_ * 2);
  // weight splits (per launch; ~28 MB, ~15 µs)
  _Float16* w1h = (_Float16*)alloc((size_t)H_ * DIN_ * 2);
  _Float16* w1l = (_Float16*)alloc((size_t)H_ * DIN_ * 2);
  _Float16* w2h = (_Float16*)alloc((size_t)H_ * H_ * 2);
  _Float16* w2l = (_Float16*)alloc((size_t)H_ * H_ * 2);
  _Float16* w3h = (_Float16*)alloc((size_t)H_ * H_ * 2);
  _Float16* w3l = (_Float16*)alloc((size_t)H_ * H_ * 2);
  _Float16* wihh = (_Float16*)alloc((size_t)3 * H_ * H_ * 2);
  _Float16* wihl = (_Float16*)alloc((size_t)3 * H_ * H_ * 2);
  _Float16* whhh = (_Float16*)alloc((size_t)3 * H_ * H_ * 2);
  _Float16* whhl = (_Float16*)alloc((size_t)3 * H_ * H_ * 2);
  _Float16* whhi = (_Float16*)alloc((size_t)APAD_ * H_ * 2);  // Wh hi only (1-pass)
  float* wmaxsq = (float*)alloc(4);

  float* outf  = (float*)d_out;
  float* atomp = outf + 2 * B_;

  (void)hipMemsetAsync(d_out, 0, (size_t)out_size * sizeof(float), stream);
  (void)hipMemsetAsync(wmaxsq, 0, 4, stream);

  auto psgrid = [](int rpad, int k) { return (rpad * k / 4 + 255) / 256; };
  presplit<<<psgrid(H_, DIN_), 256, 0, stream>>>(W1, w1h, w1l, H_, H_, DIN_);
  presplit<<<psgrid(H_, H_), 256, 0, stream>>>(W2, w2h, w2l, H_, H_, H_);
  presplit<<<psgrid(H_, H_), 256, 0, stream>>>(W3, w3h, w3l, H_, H_, H_);
  presplit<<<psgrid(3 * H_, H_), 256, 0, stream>>>(Wih, wihh, wihl, 3 * H_, 3 * H_, H_);
  presplit<<<psgrid(3 * H_, H_), 256, 0, stream>>>(Whh, whhh, whhl, 3 * H_, 3 * H_, H_);
  presplit<<<psgrid(APAD_, H_), 256, 0, stream>>>(Wh, whhi, nullptr, A_, APAD_, H_);

  mask_init<<<B_, 256, 0, stream>>>(xmask, mask);
  wmax_k<<<A_, 256, 0, stream>>>(Wh, wmaxsq);
  split4_k<<<(B_ * DIN_ / 4 + 255) / 256, 256, 0, stream>>>(x, xh, xl, B_ * DIN_ / 4);

  // base MLP: x -> t1 -> t2 -> cls (fp32 + split into curh/curl)
  gemmA<1, 0, 1, 3><<<dim3(H_ / 128, B_ / 128), 256, 0, stream>>>(
      xh, xl, w1h, w1l, b1, nullptr, t1h, t1l, B_, H_, DIN_);
  gemmA<1, 0, 1, 3><<<dim3(H_ / 128, B_ / 128), 256, 0, stream>>>(
      t1h, t1l, w2h, w2l, b2, nullptr, t2h, t2l, B_, H_, H_);
  gemmA<0, 1, 1, 3><<<dim3(H_ / 128, B_ / 128), 256, 0, stream>>>(
      t2h, t2l, w3h, w3l, b3, cls, curh, curl, B_, H_, H_);

  uint32_t fk0[RL_], fk1[RL_];
  for (int j = 0; j < RL_; ++j)
    threefry2x32(0u, 42u, 0u, (uint32_t)j, &fk0[j], &fk1[j]);

  for (int j = 0; j < RL_; ++j) {
    gemmA<0, 1, 0, 3><<<dim3(3 * H_ / 128, B_ / 128), 256, 0, stream>>>(
        curh, curl, wihh, wihl, bih, gi, nullptr, nullptr, B_, 3 * H_, H_);
    if (j > 0)
      gemmA<0, 1, 0, 3><<<dim3(3 * H_ / 128, B_ / 128), 256, 0, stream>>>(
          hh_, hl_, whhh, whhl, bhh, gh, nullptr, nullptr, B_, 3 * H_, H_);
    gru_elem<<<(B_ * H_ + 255) / 256, 256, 0, stream>>>(gi, gh, bhh, hbuf, hh_, hl_,
                                                        j == 0 ? 1 : 0);
    gemmA<0, 1, 0, 1><<<dim3(APAD_ / 128, B_ / 128), 256, 0, stream>>>(
        hh_, nullptr, whhi, nullptr, bh, logits, nullptr, nullptr, B_, A_, H_);
    select_step<<<B_, 256, 0, stream>>>(logits, mask, idxs, cls, ae, curh, curl,
                                        atomp, hbuf, Wh, bh, wmaxsq,
                                        fk0[j], fk1[j], j);
  }

  head_k<<<B_, 256, 0, stream>>>(idxs, ae, w_mu, b_mu, w_cov, b_cov, alpha, outf);
}